// Round 1
// baseline (1200.892 us; speedup 1.0000x reference)
//
#include <hip/hip_runtime.h>
#include <hip/hip_bf16.h>

#define D_MODEL 256
#define N_HEADS 8
#define HD 32
#define NQ 900
#define BS 4
#define MROWS (NQ * BS)          // 3600
#define HW_TOT 21760
#define VROWS (HW_TOT * BS)      // 87040

// ---------------------------------------------------------------- add
__global__ __launch_bounds__(256) void add_kernel(const float* __restrict__ a,
                                                  const float* __restrict__ b,
                                                  float* __restrict__ o, int n) {
  int i = blockIdx.x * 256 + threadIdx.x;
  if (i < n) o[i] = a[i] + b[i];
}

// ---------------------------------------------------------------- GEMM
// out[M,N] = X[M,K] @ W[N,K]^T + bias[N]; optional ReLU.
// 64x64 tile, 256 threads, 4x4 microtile, BK=16.
__global__ __launch_bounds__(256) void gemm_bias(const float* __restrict__ X,
                                                 const float* __restrict__ W,
                                                 const float* __restrict__ bias,
                                                 float* __restrict__ out,
                                                 int M, int N, int K, int relu) {
  __shared__ float sX[16][65];
  __shared__ float sW[16][65];
  const int tid = threadIdx.x;
  const int m0 = blockIdx.x * 64;
  const int n0 = blockIdx.y * 64;
  const int tm = (tid >> 4) << 2;   // 0..60
  const int tn = (tid & 15) << 2;   // 0..60
  const int lm = tid >> 2;          // 0..63
  const int lk = (tid & 3) << 2;    // 0,4,8,12

  float acc[4][4] = {};
  const int gm = m0 + lm;
  const int gn = n0 + lm;

  for (int k0 = 0; k0 < K; k0 += 16) {
    float4 xv = make_float4(0.f, 0.f, 0.f, 0.f);
    if (gm < M) xv = *reinterpret_cast<const float4*>(X + (size_t)gm * K + k0 + lk);
    sX[lk + 0][lm] = xv.x; sX[lk + 1][lm] = xv.y;
    sX[lk + 2][lm] = xv.z; sX[lk + 3][lm] = xv.w;
    float4 wv = make_float4(0.f, 0.f, 0.f, 0.f);
    if (gn < N) wv = *reinterpret_cast<const float4*>(W + (size_t)gn * K + k0 + lk);
    sW[lk + 0][lm] = wv.x; sW[lk + 1][lm] = wv.y;
    sW[lk + 2][lm] = wv.z; sW[lk + 3][lm] = wv.w;
    __syncthreads();
#pragma unroll
    for (int kk = 0; kk < 16; ++kk) {
      float a[4], bb[4];
#pragma unroll
      for (int i = 0; i < 4; ++i) a[i] = sX[kk][tm + i];
#pragma unroll
      for (int j = 0; j < 4; ++j) bb[j] = sW[kk][tn + j];
#pragma unroll
      for (int i = 0; i < 4; ++i)
#pragma unroll
        for (int j = 0; j < 4; ++j) acc[i][j] += a[i] * bb[j];
    }
    __syncthreads();
  }

#pragma unroll
  for (int i = 0; i < 4; ++i) {
    int om = m0 + tm + i;
    if (om >= M) continue;
#pragma unroll
    for (int j = 0; j < 4; ++j) {
      int on = n0 + tn + j;
      if (on >= N) continue;
      float v = acc[i][j] + bias[on];
      if (relu) v = fmaxf(v, 0.f);
      out[(size_t)om * N + on] = v;
    }
  }
}

// ---------------------------------------------------------------- self-attention
// Q,K,V buffers: (3600, 256) with row = q*4+b, col = h*32+d.
// One block = one (b,h) and 8 queries. 256 threads = 8 groups x 32 lanes.
#define QPB 8
__global__ __launch_bounds__(256) void attn_kernel(const float* __restrict__ Q,
                                                   const float* __restrict__ K,
                                                   const float* __restrict__ V,
                                                   float* __restrict__ O) {
  __shared__ float sS[QPB][NQ];
  __shared__ float sQ[QPB][HD];
  const int bh = blockIdx.x;
  const int b = bh >> 3;
  const int h = bh & 7;
  const int q0 = blockIdx.y * QPB;
  const int tid = threadIdx.x;
  const int qi = tid >> 5;
  const int lane = tid & 31;
  const int q = q0 + qi;
  const bool qvalid = (q < NQ);
  const int col = h * HD;

  if (qvalid) sQ[qi][lane] = Q[((size_t)(q * 4 + b)) * D_MODEL + col + lane];
  __syncthreads();

  const float scale = 0.17677669529663687f;  // 1/sqrt(32)
  if (qvalid) {
    for (int kk = lane; kk < NQ; kk += 32) {
      const float* kr = K + ((size_t)(kk * 4 + b)) * D_MODEL + col;
      float dot = 0.f;
#pragma unroll
      for (int d = 0; d < HD; ++d) dot += sQ[qi][d] * kr[d];
      sS[qi][kk] = dot * scale;
    }
  }
  __syncthreads();

  float mx = -1e30f;
  if (qvalid)
    for (int kk = lane; kk < NQ; kk += 32) mx = fmaxf(mx, sS[qi][kk]);
#pragma unroll
  for (int off = 16; off; off >>= 1) mx = fmaxf(mx, __shfl_xor(mx, off));
  float sum = 0.f;
  if (qvalid)
    for (int kk = lane; kk < NQ; kk += 32) {
      float p = __expf(sS[qi][kk] - mx);
      sS[qi][kk] = p;
      sum += p;
    }
#pragma unroll
  for (int off = 16; off; off >>= 1) sum += __shfl_xor(sum, off);
  float rs = 1.f / sum;

  if (qvalid) {
    float acc = 0.f;
    for (int kk = 0; kk < NQ; ++kk)
      acc += sS[qi][kk] * V[((size_t)(kk * 4 + b)) * D_MODEL + col + lane];
    O[((size_t)(q * 4 + b)) * D_MODEL + col + lane] = acc * rs;
  }
}

// ---------------------------------------------------------------- residual + LN
__global__ __launch_bounds__(256) void ln_kernel(const float* __restrict__ A,
                                                 const float* __restrict__ B,
                                                 const float* __restrict__ g,
                                                 const float* __restrict__ bb,
                                                 float* __restrict__ out) {
  const int row = blockIdx.x;
  const int t = threadIdx.x;
  const size_t base = (size_t)row * D_MODEL;
  float x = A[base + t] + B[base + t];
  float s = x, s2 = x * x;
#pragma unroll
  for (int off = 32; off; off >>= 1) {
    s += __shfl_xor(s, off);
    s2 += __shfl_xor(s2, off);
  }
  __shared__ float wsum[4], wsum2[4];
  const int w = t >> 6;
  if ((t & 63) == 0) { wsum[w] = s; wsum2[w] = s2; }
  __syncthreads();
  s = wsum[0] + wsum[1] + wsum[2] + wsum[3];
  s2 = wsum2[0] + wsum2[1] + wsum2[2] + wsum2[3];
  const float mu = s * (1.f / 256.f);
  const float var = s2 * (1.f / 256.f) - mu * mu;
  const float inv = rsqrtf(var + 1e-5f);
  out[base + t] = (x - mu) * inv * g[t] + bb[t];
}

// ---------------------------------------------------------------- MS-deform sampling
// value: (87040, 256) row = pos*4+b, col = h*32+d
// offs:  (3600, 256)  row = q*4+b,  col = h*32 + (l*4+p)*2 + c
// awraw: (3600, 128)  col = h*16 + l*4 + p
// refp:  (900,4,4,2)  idx = (row*4 + l)*2 + c
// out:   (3600, 256)
__global__ __launch_bounds__(256) void msds_kernel(const float* __restrict__ value,
                                                   const float* __restrict__ offs,
                                                   const float* __restrict__ awraw,
                                                   const float* __restrict__ refp,
                                                   float* __restrict__ out) {
  const int gid = blockIdx.x * 256 + threadIdx.x;
  const int row = gid >> 8;   // q*4+b
  const int col = gid & 255;
  const int h = col >> 5;
  const int d = col & 31;
  const int b = row & 3;

  const int WL[4] = {128, 64, 32, 16};
  const int HL[4] = {128, 64, 32, 16};
  const int ST[4] = {0, 16384, 20480, 21504};

  // attention-weight softmax (redundant across the 32 d-lanes of a head)
  const float* awp = awraw + (size_t)row * 128 + h * 16;
  float awv[16];
  float m = -1e30f;
#pragma unroll
  for (int i = 0; i < 16; ++i) { awv[i] = awp[i]; m = fmaxf(m, awv[i]); }
  float s = 0.f;
#pragma unroll
  for (int i = 0; i < 16; ++i) { awv[i] = __expf(awv[i] - m); s += awv[i]; }
  const float invs = 1.f / s;

  const float* offp = offs + (size_t)row * D_MODEL + h * HD;
  float acc = 0.f;
#pragma unroll
  for (int l = 0; l < 4; ++l) {
    const int wl = WL[l], hl = HL[l], st = ST[l];
    const float rx = refp[((size_t)row * 4 + l) * 2 + 0];
    const float ry = refp[((size_t)row * 4 + l) * 2 + 1];
#pragma unroll
    for (int p = 0; p < 4; ++p) {
      const float ox = offp[(l * 4 + p) * 2 + 0];
      const float oy = offp[(l * 4 + p) * 2 + 1];
      const float x = (rx + ox / (float)wl) * (float)wl - 0.5f;
      const float y = (ry + oy / (float)hl) * (float)hl - 0.5f;
      const float x0f = floorf(x), y0f = floorf(y);
      const int x0 = (int)x0f, y0 = (int)y0f;
      const float fx = x - x0f, fy = y - y0f;
      const float a = awv[l * 4 + p] * invs;
      const float w00 = (1.f - fx) * (1.f - fy);
      const float w10 = fx * (1.f - fy);
      const float w01 = (1.f - fx) * fy;
      const float w11 = fx * fy;
      float sum = 0.f;
      {
        int ix = x0, iy = y0;
        if (ix >= 0 && ix < wl && iy >= 0 && iy < hl)
          sum += w00 * value[((size_t)((st + iy * wl + ix) * 4 + b)) * D_MODEL + h * HD + d];
      }
      {
        int ix = x0 + 1, iy = y0;
        if (ix >= 0 && ix < wl && iy >= 0 && iy < hl)
          sum += w10 * value[((size_t)((st + iy * wl + ix) * 4 + b)) * D_MODEL + h * HD + d];
      }
      {
        int ix = x0, iy = y0 + 1;
        if (ix >= 0 && ix < wl && iy >= 0 && iy < hl)
          sum += w01 * value[((size_t)((st + iy * wl + ix) * 4 + b)) * D_MODEL + h * HD + d];
      }
      {
        int ix = x0 + 1, iy = y0 + 1;
        if (ix >= 0 && ix < wl && iy >= 0 && iy < hl)
          sum += w11 * value[((size_t)((st + iy * wl + ix) * 4 + b)) * D_MODEL + h * HD + d];
      }
      acc += a * sum;
    }
  }
  out[(size_t)row * D_MODEL + col] = acc;
}

// ---------------------------------------------------------------- launch
extern "C" void kernel_launch(void* const* d_in, const int* in_sizes, int n_in,
                              void* d_out, int out_size, void* d_ws, size_t ws_size,
                              hipStream_t stream) {
  const float* tgt      = (const float*)d_in[0];
  const float* qpos     = (const float*)d_in[1];
  const float* memory   = (const float*)d_in[2];
  const float* refp     = (const float*)d_in[3];
  const float* sa_in_w  = (const float*)d_in[4];
  const float* sa_in_b  = (const float*)d_in[5];
  const float* sa_out_w = (const float*)d_in[6];
  const float* sa_out_b = (const float*)d_in[7];
  const float* ln1_g = (const float*)d_in[8];
  const float* ln1_b = (const float*)d_in[9];
  const float* ln2_g = (const float*)d_in[10];
  const float* ln2_b = (const float*)d_in[11];
  const float* ln3_g = (const float*)d_in[12];
  const float* ln3_b = (const float*)d_in[13];
  const float* so_w = (const float*)d_in[14];
  const float* so_b = (const float*)d_in[15];
  const float* aw_w = (const float*)d_in[16];
  const float* aw_b = (const float*)d_in[17];
  const float* vp_w = (const float*)d_in[18];
  const float* vp_b = (const float*)d_in[19];
  const float* op_w = (const float*)d_in[20];
  const float* op_b = (const float*)d_in[21];
  const float* ff1_w = (const float*)d_in[22];
  const float* ff1_b = (const float*)d_in[23];
  const float* ff2_w = (const float*)d_in[24];
  const float* ff2_b = (const float*)d_in[25];

  float* out = (float*)d_out;
  float* ws = (float*)d_ws;

  float* value = ws;                       // 22282240 floats; later reused as FFN hidden
  float* A = ws + (size_t)VROWS * 256;     // 921600 each below
  float* B = A + (size_t)MROWS * 256;
  float* C = B + (size_t)MROWS * 256;
  float* D = C + (size_t)MROWS * 256;
  float* E = D + (size_t)MROWS * 256;
  float* F = E + (size_t)MROWS * 256;

  const int nElem = MROWS * 256;

  auto gemm = [&](const float* X, const float* W, const float* bias, float* O,
                  int M, int N, int K, int relu) {
    dim3 g((M + 63) / 64, (N + 63) / 64);
    gemm_bias<<<g, 256, 0, stream>>>(X, W, bias, O, M, N, K, relu);
  };

  // 1. qk = tgt + query_pos
  add_kernel<<<nElem / 256, 256, 0, stream>>>(tgt, qpos, A, nElem);
  // 2-4. q,k,v projections
  gemm(A, sa_in_w, sa_in_b, B, MROWS, 256, 256, 0);                    // q
  gemm(A, sa_in_w + 256 * 256, sa_in_b + 256, C, MROWS, 256, 256, 0);  // k
  gemm(tgt, sa_in_w + 512 * 256, sa_in_b + 512, D, MROWS, 256, 256, 0);// v
  // 5. self-attention -> A
  attn_kernel<<<dim3(BS * N_HEADS, (NQ + QPB - 1) / QPB), 256, 0, stream>>>(B, C, D, A);
  // 6. sa projection -> E
  gemm(A, sa_out_w, sa_out_b, E, MROWS, 256, 256, 0);
  // 7. tgt2 = LN(tgt + sa) [ln2] -> F
  ln_kernel<<<MROWS, 256, 0, stream>>>(tgt, E, ln2_g, ln2_b, F);
  // 8. q2 = tgt2 + query_pos -> A
  add_kernel<<<nElem / 256, 256, 0, stream>>>(F, qpos, A, nElem);
  // 9-10. sampling offsets + attention weights
  gemm(A, so_w, so_b, B, MROWS, 256, 256, 0);
  gemm(A, aw_w, aw_b, C, MROWS, 128, 256, 0);
  // 11. value projection (the big one)
  gemm(memory, vp_w, vp_b, value, VROWS, 256, 256, 0);
  // 12. deformable sampling -> D
  msds_kernel<<<MROWS, 256, 0, stream>>>(value, B, C, refp, D);
  // 13. output projection -> E
  gemm(D, op_w, op_b, E, MROWS, 256, 256, 0);
  // 14. tgt3 = LN(tgt2 + ca) [ln1] -> C
  ln_kernel<<<MROWS, 256, 0, stream>>>(F, E, ln1_g, ln1_b, C);
  // 15. FFN hidden = relu(tgt3 @ ff1^T + b) -> value (reused)
  gemm(C, ff1_w, ff1_b, value, MROWS, 2048, 256, 1);
  // 16. ff2 -> D
  gemm(value, ff2_w, ff2_b, D, MROWS, 256, 2048, 0);
  // 17. out = LN(tgt3 + ff) [ln3]
  ln_kernel<<<MROWS, 256, 0, stream>>>(C, D, ln3_g, ln3_b, out);
}

// Round 2
// 404.899 us; speedup vs baseline: 2.9659x; 2.9659x over previous
//
#include <hip/hip_runtime.h>
#include <hip/hip_bf16.h>

#define D_MODEL 256
#define N_HEADS 8
#define HD 32
#define NQ 900
#define BS 4
#define MROWS (NQ * BS)          // 3600
#define HW_TOT 21760
#define VROWS (HW_TOT * BS)      // 87040

typedef __attribute__((ext_vector_type(8))) short bf16x8;
typedef __attribute__((ext_vector_type(4))) float f32x4;

__device__ inline short f2b(float f) {
  union { __hip_bfloat16 h; short s; } u;
  u.h = __float2bfloat16(f);
  return u.s;
}
__device__ inline bf16x8 bzero8() {
  bf16x8 v;
#pragma unroll
  for (int j = 0; j < 8; ++j) v[j] = 0;
  return v;
}
__device__ inline f32x4 fzero4() {
  f32x4 v;
#pragma unroll
  for (int j = 0; j < 4; ++j) v[j] = 0.f;
  return v;
}
__device__ inline bf16x8 ldcvt8(const float* __restrict__ p) {
  float4 a = *reinterpret_cast<const float4*>(p);
  float4 b = *reinterpret_cast<const float4*>(p + 4);
  bf16x8 r;
  r[0] = f2b(a.x); r[1] = f2b(a.y); r[2] = f2b(a.z); r[3] = f2b(a.w);
  r[4] = f2b(b.x); r[5] = f2b(b.y); r[6] = f2b(b.z); r[7] = f2b(b.w);
  return r;
}

// ---------------------------------------------------------------- add
__global__ __launch_bounds__(256) void add_kernel(const float* __restrict__ a,
                                                  const float* __restrict__ b,
                                                  float* __restrict__ o, int n) {
  int i = blockIdx.x * 256 + threadIdx.x;
  if (i < n) o[i] = a[i] + b[i];
}

// ---------------------------------------------------------------- MFMA GEMM
// out[M,N] = X[M,K] @ W[N,K]^T + bias[N], bf16 MFMA, fp32 I/O.
// 256 threads = 4 waves. Wave handles (BM/4) rows x BN cols.
template <int BM, int BN, int RELU>
__global__ __launch_bounds__(256) void mfma_gemm(const float* __restrict__ X,
                                                 const float* __restrict__ W,
                                                 const float* __restrict__ bias,
                                                 float* __restrict__ out,
                                                 int M, int N, int K) {
  constexpr int NF = BN / 16;
  constexpr int MF = BM / 64;
  __shared__ short sA[BM][40];  // +8 bf16 pad: row stride 80B kills conflicts
  __shared__ short sB[BN][40];
  const int tid = threadIdx.x;
  const int wave = tid >> 6, lane = tid & 63;
  const int l15 = lane & 15, l4 = lane >> 4;
  const int m0 = blockIdx.x * BM, n0 = blockIdx.y * BN;
  const int wr = wave * (BM / 4);

  f32x4 acc[MF][NF];
#pragma unroll
  for (int mi = 0; mi < MF; ++mi)
#pragma unroll
    for (int f = 0; f < NF; ++f) acc[mi][f] = fzero4();

  for (int k0 = 0; k0 < K; k0 += 32) {
#pragma unroll
    for (int c = tid; c < BM * 4; c += 256) {
      int row = c >> 2, kof = (c & 3) * 8;
      int m = m0 + row;
      bf16x8 v = bzero8();
      if (m < M) v = ldcvt8(X + (size_t)m * K + k0 + kof);
      *reinterpret_cast<bf16x8*>(&sA[row][kof]) = v;
    }
#pragma unroll
    for (int c = tid; c < BN * 4; c += 256) {
      int row = c >> 2, kof = (c & 3) * 8;
      int n = n0 + row;
      bf16x8 v = bzero8();
      if (n < N) v = ldcvt8(W + (size_t)n * K + k0 + kof);
      *reinterpret_cast<bf16x8*>(&sB[row][kof]) = v;
    }
    __syncthreads();
    bf16x8 av[MF];
#pragma unroll
    for (int mi = 0; mi < MF; ++mi)
      av[mi] = *reinterpret_cast<bf16x8*>(&sA[wr + mi * 16 + l15][l4 * 8]);
#pragma unroll
    for (int f = 0; f < NF; ++f) {
      bf16x8 bv = *reinterpret_cast<bf16x8*>(&sB[f * 16 + l15][l4 * 8]);
#pragma unroll
      for (int mi = 0; mi < MF; ++mi)
        acc[mi][f] = __builtin_amdgcn_mfma_f32_16x16x32_bf16(av[mi], bv, acc[mi][f], 0, 0, 0);
    }
    __syncthreads();
  }

#pragma unroll
  for (int f = 0; f < NF; ++f) {
    int col = n0 + f * 16 + l15;
    if (col >= N) continue;
    float bb = bias[col];
#pragma unroll
    for (int mi = 0; mi < MF; ++mi) {
#pragma unroll
      for (int i = 0; i < 4; ++i) {
        int row = m0 + wr + mi * 16 + l4 * 4 + i;
        if (row >= M) continue;
        float v = acc[mi][f][i] + bb;
        if (RELU) v = fmaxf(v, 0.f);
        out[(size_t)row * N + col] = v;
      }
    }
  }
}

// ---------------------------------------------------------------- flash attention
// Q,K,V fp32 (3600,256): row = q*4+b, col = h*32+d.
// Block = (b,h, 64-query tile); 4 waves x 16 rows. hd=32 = one MFMA K-step.
__global__ __launch_bounds__(256) void flash_attn(const float* __restrict__ Q,
                                                  const float* __restrict__ K,
                                                  const float* __restrict__ V,
                                                  float* __restrict__ O) {
  const int bh = blockIdx.x, b = bh >> 3, h = bh & 7;
  const int q0 = blockIdx.y * 64;
  const int tid = threadIdx.x, wave = tid >> 6, lane = tid & 63;
  const int l15 = lane & 15, l4 = lane >> 4;
  const int cb = h * 32;

  __shared__ short sQ[64][40];
  __shared__ short sK[64][40];
  __shared__ short sVt[32][72];  // V transposed: [d][key]
  __shared__ short sP[64][72];

  {  // stage Q tile
    int row = tid >> 2, kof = (tid & 3) * 8;
    int q = q0 + row;
    bf16x8 v = bzero8();
    if (q < NQ) v = ldcvt8(Q + (size_t)(q * 4 + b) * D_MODEL + cb + kof);
    *reinterpret_cast<bf16x8*>(&sQ[row][kof]) = v;
  }
  __syncthreads();
  const int wr = wave * 16;
  const bf16x8 aq = *reinterpret_cast<bf16x8*>(&sQ[wr + l15][l4 * 8]);

  float mrow[4], lrow[4];
#pragma unroll
  for (int i = 0; i < 4; ++i) { mrow[i] = -1e30f; lrow[i] = 0.f; }
  f32x4 accO[2];
  accO[0] = fzero4(); accO[1] = fzero4();

  for (int kt = 0; kt < 15; ++kt) {
    const int k0 = kt * 64;
    {  // stage K tile
      int row = tid >> 2, kof = (tid & 3) * 8;
      int kk = k0 + row;
      bf16x8 v = bzero8();
      if (kk < NQ) v = ldcvt8(K + (size_t)(kk * 4 + b) * D_MODEL + cb + kof);
      *reinterpret_cast<bf16x8*>(&sK[row][kof]) = v;
    }
    {  // stage V tile transposed
      int row = tid >> 2, dof = (tid & 3) * 8;
      int kk = k0 + row;
      if (kk < NQ) {
        const float* p = V + (size_t)(kk * 4 + b) * D_MODEL + cb + dof;
        float4 a = *reinterpret_cast<const float4*>(p);
        float4 c4 = *reinterpret_cast<const float4*>(p + 4);
        sVt[dof + 0][row] = f2b(a.x);  sVt[dof + 1][row] = f2b(a.y);
        sVt[dof + 2][row] = f2b(a.z);  sVt[dof + 3][row] = f2b(a.w);
        sVt[dof + 4][row] = f2b(c4.x); sVt[dof + 5][row] = f2b(c4.y);
        sVt[dof + 6][row] = f2b(c4.z); sVt[dof + 7][row] = f2b(c4.w);
      } else {
#pragma unroll
        for (int j = 0; j < 8; ++j) sVt[dof + j][row] = 0;
      }
    }
    __syncthreads();

    // S = Q K^T (16x64 per wave)
    f32x4 s[4];
#pragma unroll
    for (int f = 0; f < 4; ++f) {
      bf16x8 bk = *reinterpret_cast<bf16x8*>(&sK[f * 16 + l15][l4 * 8]);
      s[f] = __builtin_amdgcn_mfma_f32_16x16x32_bf16(aq, bk, fzero4(), 0, 0, 0);
    }
    // scale + column mask
#pragma unroll
    for (int f = 0; f < 4; ++f) {
      bool valid = (k0 + f * 16 + l15) < NQ;
#pragma unroll
      for (int i = 0; i < 4; ++i) {
        float sv = s[f][i] * 0.17677669529663687f;
        s[f][i] = valid ? sv : -1e30f;
      }
    }
    // row max across 64 cols (4 frags + 16-lane butterfly)
    float mx[4];
#pragma unroll
    for (int i = 0; i < 4; ++i)
      mx[i] = fmaxf(fmaxf(s[0][i], s[1][i]), fmaxf(s[2][i], s[3][i]));
#pragma unroll
    for (int off = 1; off < 16; off <<= 1)
#pragma unroll
      for (int i = 0; i < 4; ++i) mx[i] = fmaxf(mx[i], __shfl_xor(mx[i], off));

    float alpha[4], rs[4];
#pragma unroll
    for (int i = 0; i < 4; ++i) {
      float mn = fmaxf(mrow[i], mx[i]);
      alpha[i] = __expf(mrow[i] - mn);
      mrow[i] = mn;
      rs[i] = 0.f;
    }
    // P = exp(S - m), write to LDS in A-layout, accumulate row sums
#pragma unroll
    for (int f = 0; f < 4; ++f)
#pragma unroll
      for (int i = 0; i < 4; ++i) {
        float p = __expf(s[f][i] - mrow[i]);
        rs[i] += p;
        sP[wr + l4 * 4 + i][f * 16 + l15] = f2b(p);
      }
#pragma unroll
    for (int off = 1; off < 16; off <<= 1)
#pragma unroll
      for (int i = 0; i < 4; ++i) rs[i] += __shfl_xor(rs[i], off);
#pragma unroll
    for (int i = 0; i < 4; ++i) lrow[i] = lrow[i] * alpha[i] + rs[i];
#pragma unroll
    for (int nf = 0; nf < 2; ++nf)
#pragma unroll
      for (int i = 0; i < 4; ++i) accO[nf][i] *= alpha[i];

    // O += P V  (P: 16x64, V: 64x32 -> two K-steps, two d-frags)
#pragma unroll
    for (int ks = 0; ks < 2; ++ks) {
      bf16x8 ap = *reinterpret_cast<bf16x8*>(&sP[wr + l15][ks * 32 + l4 * 8]);
#pragma unroll
      for (int nf = 0; nf < 2; ++nf) {
        bf16x8 bv = *reinterpret_cast<bf16x8*>(&sVt[nf * 16 + l15][ks * 32 + l4 * 8]);
        accO[nf] = __builtin_amdgcn_mfma_f32_16x16x32_bf16(ap, bv, accO[nf], 0, 0, 0);
      }
    }
    __syncthreads();
  }

#pragma unroll
  for (int nf = 0; nf < 2; ++nf)
#pragma unroll
    for (int i = 0; i < 4; ++i) {
      int q = q0 + wr + l4 * 4 + i;
      if (q < NQ)
        O[(size_t)(q * 4 + b) * D_MODEL + cb + nf * 16 + l15] = accO[nf][i] / lrow[i];
    }
}

// ---------------------------------------------------------------- residual + LN
__global__ __launch_bounds__(256) void ln_kernel(const float* __restrict__ A,
                                                 const float* __restrict__ B,
                                                 const float* __restrict__ g,
                                                 const float* __restrict__ bb,
                                                 float* __restrict__ out) {
  const int row = blockIdx.x;
  const int t = threadIdx.x;
  const size_t base = (size_t)row * D_MODEL;
  float x = A[base + t] + B[base + t];
  float s = x, s2 = x * x;
#pragma unroll
  for (int off = 32; off; off >>= 1) {
    s += __shfl_xor(s, off);
    s2 += __shfl_xor(s2, off);
  }
  __shared__ float wsum[4], wsum2[4];
  const int w = t >> 6;
  if ((t & 63) == 0) { wsum[w] = s; wsum2[w] = s2; }
  __syncthreads();
  s = wsum[0] + wsum[1] + wsum[2] + wsum[3];
  s2 = wsum2[0] + wsum2[1] + wsum2[2] + wsum2[3];
  const float mu = s * (1.f / 256.f);
  const float var = s2 * (1.f / 256.f) - mu * mu;
  const float inv = rsqrtf(var + 1e-5f);
  out[base + t] = (x - mu) * inv * g[t] + bb[t];
}

// ---------------------------------------------------------------- MS-deform sampling
__global__ __launch_bounds__(256) void msds_kernel(const float* __restrict__ value,
                                                   const float* __restrict__ offs,
                                                   const float* __restrict__ awraw,
                                                   const float* __restrict__ refp,
                                                   float* __restrict__ out) {
  const int gid = blockIdx.x * 256 + threadIdx.x;
  const int row = gid >> 8;   // q*4+b
  const int col = gid & 255;
  const int h = col >> 5;
  const int d = col & 31;
  const int b = row & 3;

  const int WL[4] = {128, 64, 32, 16};
  const int HL[4] = {128, 64, 32, 16};
  const int ST[4] = {0, 16384, 20480, 21504};

  const float* awp = awraw + (size_t)row * 128 + h * 16;
  float awv[16];
  float m = -1e30f;
#pragma unroll
  for (int i = 0; i < 16; ++i) { awv[i] = awp[i]; m = fmaxf(m, awv[i]); }
  float s = 0.f;
#pragma unroll
  for (int i = 0; i < 16; ++i) { awv[i] = __expf(awv[i] - m); s += awv[i]; }
  const float invs = 1.f / s;

  const float* offp = offs + (size_t)row * D_MODEL + h * HD;
  float acc = 0.f;
#pragma unroll
  for (int l = 0; l < 4; ++l) {
    const int wl = WL[l], hl = HL[l], st = ST[l];
    const float rx = refp[((size_t)row * 4 + l) * 2 + 0];
    const float ry = refp[((size_t)row * 4 + l) * 2 + 1];
#pragma unroll
    for (int p = 0; p < 4; ++p) {
      const float ox = offp[(l * 4 + p) * 2 + 0];
      const float oy = offp[(l * 4 + p) * 2 + 1];
      const float x = (rx + ox / (float)wl) * (float)wl - 0.5f;
      const float y = (ry + oy / (float)hl) * (float)hl - 0.5f;
      const float x0f = floorf(x), y0f = floorf(y);
      const int x0 = (int)x0f, y0 = (int)y0f;
      const float fx = x - x0f, fy = y - y0f;
      const float a = awv[l * 4 + p] * invs;
      const float w00 = (1.f - fx) * (1.f - fy);
      const float w10 = fx * (1.f - fy);
      const float w01 = (1.f - fx) * fy;
      const float w11 = fx * fy;
      float sum = 0.f;
      if (x0 >= 0 && x0 < wl && y0 >= 0 && y0 < hl)
        sum += w00 * value[((size_t)((st + y0 * wl + x0) * 4 + b)) * D_MODEL + h * HD + d];
      if (x0 + 1 >= 0 && x0 + 1 < wl && y0 >= 0 && y0 < hl)
        sum += w10 * value[((size_t)((st + y0 * wl + x0 + 1) * 4 + b)) * D_MODEL + h * HD + d];
      if (x0 >= 0 && x0 < wl && y0 + 1 >= 0 && y0 + 1 < hl)
        sum += w01 * value[((size_t)((st + (y0 + 1) * wl + x0) * 4 + b)) * D_MODEL + h * HD + d];
      if (x0 + 1 >= 0 && x0 + 1 < wl && y0 + 1 >= 0 && y0 + 1 < hl)
        sum += w11 * value[((size_t)((st + (y0 + 1) * wl + x0 + 1) * 4 + b)) * D_MODEL + h * HD + d];
      acc += a * sum;
    }
  }
  out[(size_t)row * D_MODEL + col] = acc;
}

// ---------------------------------------------------------------- launch
extern "C" void kernel_launch(void* const* d_in, const int* in_sizes, int n_in,
                              void* d_out, int out_size, void* d_ws, size_t ws_size,
                              hipStream_t stream) {
  const float* tgt      = (const float*)d_in[0];
  const float* qpos     = (const float*)d_in[1];
  const float* memory   = (const float*)d_in[2];
  const float* refp     = (const float*)d_in[3];
  const float* sa_in_w  = (const float*)d_in[4];
  const float* sa_in_b  = (const float*)d_in[5];
  const float* sa_out_w = (const float*)d_in[6];
  const float* sa_out_b = (const float*)d_in[7];
  const float* ln1_g = (const float*)d_in[8];
  const float* ln1_b = (const float*)d_in[9];
  const float* ln2_g = (const float*)d_in[10];
  const float* ln2_b = (const float*)d_in[11];
  const float* ln3_g = (const float*)d_in[12];
  const float* ln3_b = (const float*)d_in[13];
  const float* so_w = (const float*)d_in[14];
  const float* so_b = (const float*)d_in[15];
  const float* aw_w = (const float*)d_in[16];
  const float* aw_b = (const float*)d_in[17];
  const float* vp_w = (const float*)d_in[18];
  const float* vp_b = (const float*)d_in[19];
  const float* op_w = (const float*)d_in[20];
  const float* op_b = (const float*)d_in[21];
  const float* ff1_w = (const float*)d_in[22];
  const float* ff1_b = (const float*)d_in[23];
  const float* ff2_w = (const float*)d_in[24];
  const float* ff2_b = (const float*)d_in[25];

  float* out = (float*)d_out;
  float* ws = (float*)d_ws;

  float* value = ws;                       // 22282240 floats; reused as FFN hidden
  float* A = ws + (size_t)VROWS * 256;
  float* B = A + (size_t)MROWS * 256;
  float* C = B + (size_t)MROWS * 256;
  float* D = C + (size_t)MROWS * 256;
  float* E = D + (size_t)MROWS * 256;
  float* F = E + (size_t)MROWS * 256;

  const int nElem = MROWS * 256;
  const dim3 gS((MROWS + 63) / 64, 4);   // M=3600, N=256
  const dim3 gAw((MROWS + 63) / 64, 2);  // N=128

  // 1. qk = tgt + query_pos
  add_kernel<<<nElem / 256, 256, 0, stream>>>(tgt, qpos, A, nElem);
  // 2-4. q,k,v projections
  mfma_gemm<64, 64, 0><<<gS, 256, 0, stream>>>(A, sa_in_w, sa_in_b, B, MROWS, 256, 256);
  mfma_gemm<64, 64, 0><<<gS, 256, 0, stream>>>(A, sa_in_w + 256 * 256, sa_in_b + 256, C, MROWS, 256, 256);
  mfma_gemm<64, 64, 0><<<gS, 256, 0, stream>>>(tgt, sa_in_w + 512 * 256, sa_in_b + 512, D, MROWS, 256, 256);
  // 5. flash attention -> A
  flash_attn<<<dim3(BS * N_HEADS, (NQ + 63) / 64), 256, 0, stream>>>(B, C, D, A);
  // 6. sa projection -> E
  mfma_gemm<64, 64, 0><<<gS, 256, 0, stream>>>(A, sa_out_w, sa_out_b, E, MROWS, 256, 256);
  // 7. tgt2 = LN(tgt + sa) [ln2] -> F
  ln_kernel<<<MROWS, 256, 0, stream>>>(tgt, E, ln2_g, ln2_b, F);
  // 8. q2 = tgt2 + query_pos -> A
  add_kernel<<<nElem / 256, 256, 0, stream>>>(F, qpos, A, nElem);
  // 9-10. sampling offsets + attention weights
  mfma_gemm<64, 64, 0><<<gS, 256, 0, stream>>>(A, so_w, so_b, B, MROWS, 256, 256);
  mfma_gemm<64, 64, 0><<<gAw, 256, 0, stream>>>(A, aw_w, aw_b, C, MROWS, 128, 256);
  // 11. value projection (M=87040)
  mfma_gemm<128, 256, 0><<<dim3(VROWS / 128, 1), 256, 0, stream>>>(memory, vp_w, vp_b, value, VROWS, 256, 256);
  // 12. deformable sampling -> D
  msds_kernel<<<MROWS, 256, 0, stream>>>(value, B, C, refp, D);
  // 13. output projection -> E
  mfma_gemm<64, 64, 0><<<gS, 256, 0, stream>>>(D, op_w, op_b, E, MROWS, 256, 256);
  // 14. tgt3 = LN(tgt2 + ca) [ln1] -> C
  ln_kernel<<<MROWS, 256, 0, stream>>>(F, E, ln1_g, ln1_b, C);
  // 15. FFN hidden = relu(tgt3 @ ff1^T + b) -> value (reused)
  mfma_gemm<128, 128, 1><<<dim3((MROWS + 127) / 128, 16), 256, 0, stream>>>(C, ff1_w, ff1_b, value, MROWS, 2048, 256);
  // 16. ff2 -> D
  mfma_gemm<64, 64, 0><<<gS, 256, 0, stream>>>(value, ff2_w, ff2_b, D, MROWS, 256, 2048);
  // 17. out = LN(tgt3 + ff) [ln3]
  ln_kernel<<<MROWS, 256, 0, stream>>>(C, D, ln3_g, ln3_b, out);
}

// Round 3
// 234.015 us; speedup vs baseline: 5.1317x; 1.7302x over previous
//
#include <hip/hip_runtime.h>
#include <hip/hip_bf16.h>

#define D_MODEL 256
#define N_HEADS 8
#define HD 32
#define NQ 900
#define BS 4
#define MROWS (NQ * BS)          // 3600
#define HW_TOT 21760
#define VROWS (HW_TOT * BS)      // 87040

typedef __attribute__((ext_vector_type(8))) short bf16x8;
typedef __attribute__((ext_vector_type(4))) float f32x4;

__device__ inline short f2b(float f) {
  union { __hip_bfloat16 h; short s; } u;
  u.h = __float2bfloat16(f);
  return u.s;
}
__device__ inline float b2f(short s) {
  union { short s; __hip_bfloat16 h; } u;
  u.s = s;
  return __bfloat162float(u.h);
}
__device__ inline bf16x8 bzero8() {
  bf16x8 v;
#pragma unroll
  for (int j = 0; j < 8; ++j) v[j] = 0;
  return v;
}
__device__ inline f32x4 fzero4() {
  f32x4 v;
#pragma unroll
  for (int j = 0; j < 4; ++j) v[j] = 0.f;
  return v;
}
__device__ inline bf16x8 ldcvt8(const float* __restrict__ p) {
  float4 a = *reinterpret_cast<const float4*>(p);
  float4 b = *reinterpret_cast<const float4*>(p + 4);
  bf16x8 r;
  r[0] = f2b(a.x); r[1] = f2b(a.y); r[2] = f2b(a.z); r[3] = f2b(a.w);
  r[4] = f2b(b.x); r[5] = f2b(b.y); r[6] = f2b(b.z); r[7] = f2b(b.w);
  return r;
}

// ------------------------------------------------ weight convert (8 segments)
__global__ __launch_bounds__(256) void cvt_weights(const float* __restrict__ s0,
                                                   const float* __restrict__ s1,
                                                   const float* __restrict__ s2,
                                                   const float* __restrict__ s3,
                                                   const float* __restrict__ s4,
                                                   const float* __restrict__ s5,
                                                   const float* __restrict__ s6,
                                                   const float* __restrict__ s7,
                                                   short* __restrict__ dst) {
  int i = blockIdx.x * 256 + threadIdx.x;
  const float* s; int off;
  if (i < 196608)      { s = s0; off = 0; }
  else if (i < 262144) { s = s1; off = 196608; }
  else if (i < 327680) { s = s2; off = 262144; }
  else if (i < 360448) { s = s3; off = 327680; }
  else if (i < 425984) { s = s4; off = 360448; }
  else if (i < 491520) { s = s5; off = 425984; }
  else if (i < 1015808){ s = s6; off = 491520; }
  else if (i < 1540096){ s = s7; off = 1015808; }
  else return;
  dst[i] = f2b(s[i - off]);
}

// ------------------------------------------------ prep: tgtb, qkb, biasSOAW
__global__ __launch_bounds__(256) void prep_kernel(const float* __restrict__ tgt,
                                                   const float* __restrict__ qpos,
                                                   short* __restrict__ tgtb,
                                                   short* __restrict__ qkb,
                                                   const float* __restrict__ so_b,
                                                   const float* __restrict__ aw_b,
                                                   float* __restrict__ biasSOAW) {
  int i = blockIdx.x * 256 + threadIdx.x;
  float t = tgt[i], p = qpos[i];
  tgtb[i] = f2b(t);
  qkb[i] = f2b(t + p);
  if (i < 384) biasSOAW[i] = (i < 256) ? so_b[i] : aw_b[i - 256];
}

// ------------------------------------------------ pipelined bf16 MFMA GEMM
// out[M,N] = X[M,K] @ W[N,K]^T + bias[N]. X bf16 (AF32=0) or fp32 (AF32=1).
// W bf16. out bf16 or fp32. BM=64 only. Double-buffered LDS, 1 barrier/K-step.
template <int BM, int BN, int AF32, int OUTF32, int RELU>
__global__ __launch_bounds__(256) void gemm2(const void* __restrict__ Xv,
                                             const short* __restrict__ W,
                                             const float* __restrict__ bias,
                                             void* __restrict__ outv,
                                             int M, int N, int K) {
  constexpr int NF = BN / 16;
  constexpr int NA = BM / 64;
  constexpr int NB = BN / 64;
  __shared__ short sA[2][BM * 32];
  __shared__ short sB[2][BN * 32];
  const int tid = threadIdx.x;
  const int wave = tid >> 6, lane = tid & 63;
  const int l15 = lane & 15, l4 = lane >> 4;
  const int m0 = blockIdx.x * BM, n0 = blockIdx.y * BN;
  const int wr = wave * (BM / 4);
  const float* Xf = (const float*)Xv;
  const short* Xh = (const short*)Xv;

  f32x4 acc[NA][NF];
#pragma unroll
  for (int mi = 0; mi < NA; ++mi)
#pragma unroll
    for (int f = 0; f < NF; ++f) acc[mi][f] = fzero4();

  bf16x8 ra[NA], rb[NB];

  auto loadT = [&](int t) {
#pragma unroll
    for (int a = 0; a < NA; ++a) {
      int c = a * 256 + tid, row = c >> 2, kof = (c & 3) * 8;
      int m = m0 + row;
      if (m < M) {
        if constexpr (AF32)
          ra[a] = ldcvt8(Xf + (size_t)m * K + t * 32 + kof);
        else
          ra[a] = *reinterpret_cast<const bf16x8*>(Xh + (size_t)m * K + t * 32 + kof);
      } else ra[a] = bzero8();
    }
#pragma unroll
    for (int bb = 0; bb < NB; ++bb) {
      int c = bb * 256 + tid, row = c >> 2, kof = (c & 3) * 8;
      rb[bb] = *reinterpret_cast<const bf16x8*>(W + (size_t)(n0 + row) * K + t * 32 + kof);
    }
  };
  auto storeT = [&](int buf) {
#pragma unroll
    for (int a = 0; a < NA; ++a) {
      int c = a * 256 + tid;
      *reinterpret_cast<bf16x8*>(&sA[buf][c * 8]) = ra[a];
    }
#pragma unroll
    for (int bb = 0; bb < NB; ++bb) {
      int c = bb * 256 + tid;
      *reinterpret_cast<bf16x8*>(&sB[buf][c * 8]) = rb[bb];
    }
  };
  auto compute = [&](int buf) {
    bf16x8 av[NA];
#pragma unroll
    for (int mi = 0; mi < NA; ++mi)
      av[mi] = *reinterpret_cast<const bf16x8*>(&sA[buf][(wr + mi * 16 + l15) * 32 + l4 * 8]);
#pragma unroll
    for (int f = 0; f < NF; ++f) {
      bf16x8 bv = *reinterpret_cast<const bf16x8*>(&sB[buf][(f * 16 + l15) * 32 + l4 * 8]);
#pragma unroll
      for (int mi = 0; mi < NA; ++mi)
        acc[mi][f] = __builtin_amdgcn_mfma_f32_16x16x32_bf16(av[mi], bv, acc[mi][f], 0, 0, 0);
    }
  };

  const int nt = K / 32;
  loadT(0);
  storeT(0);
  __syncthreads();
  int cur = 0;
  for (int t = 0; t < nt; ++t) {
    if (t + 1 < nt) loadT(t + 1);
    compute(cur);
    if (t + 1 < nt) storeT(cur ^ 1);
    __syncthreads();
    cur ^= 1;
  }

#pragma unroll
  for (int f = 0; f < NF; ++f) {
    int col = n0 + f * 16 + l15;
    float bfv = bias[col];
#pragma unroll
    for (int mi = 0; mi < NA; ++mi) {
#pragma unroll
      for (int i = 0; i < 4; ++i) {
        int row = m0 + wr + mi * 16 + l4 * 4 + i;
        if (row >= M) continue;
        float v = acc[mi][f][i] + bfv;
        if (RELU) v = fmaxf(v, 0.f);
        if constexpr (OUTF32)
          ((float*)outv)[(size_t)row * N + col] = v;
        else
          ((short*)outv)[(size_t)row * N + col] = f2b(v);
      }
    }
  }
}

// ------------------------------------------------ flash attention (bf16 I/O)
// QK: (3600,512) bf16 [Q cols 0..255, K cols 256..511], V: (3600,256) bf16.
__global__ __launch_bounds__(256) void flash_attn(const short* __restrict__ QK,
                                                  const short* __restrict__ V,
                                                  short* __restrict__ O) {
  const int bh = blockIdx.x, b = bh >> 3, h = bh & 7;
  const int q0 = blockIdx.y * 64;
  const int tid = threadIdx.x, wave = tid >> 6, lane = tid & 63;
  const int l15 = lane & 15, l4 = lane >> 4;
  const int cb = h * 32;

  __shared__ short sQ[64][40];
  __shared__ short sK[64][40];
  __shared__ short sVt[32][72];
  __shared__ short sP[64][72];

  {
    int row = tid >> 2, kof = (tid & 3) * 8;
    int q = q0 + row;
    bf16x8 v = (q < NQ) ? *reinterpret_cast<const bf16x8*>(QK + (size_t)(q * 4 + b) * 512 + cb + kof)
                        : bzero8();
    *reinterpret_cast<bf16x8*>(&sQ[row][kof]) = v;
  }
  __syncthreads();
  const int wr = wave * 16;
  const bf16x8 aq = *reinterpret_cast<bf16x8*>(&sQ[wr + l15][l4 * 8]);

  float mrow[4], lrow[4];
#pragma unroll
  for (int i = 0; i < 4; ++i) { mrow[i] = -1e30f; lrow[i] = 0.f; }
  f32x4 accO[2];
  accO[0] = fzero4(); accO[1] = fzero4();

  for (int kt = 0; kt < 15; ++kt) {
    const int k0 = kt * 64;
    {
      int row = tid >> 2, kof = (tid & 3) * 8;
      int kk = k0 + row;
      bf16x8 v = (kk < NQ)
          ? *reinterpret_cast<const bf16x8*>(QK + (size_t)(kk * 4 + b) * 512 + 256 + cb + kof)
          : bzero8();
      *reinterpret_cast<bf16x8*>(&sK[row][kof]) = v;
    }
    {
      int row = tid >> 2, dof = (tid & 3) * 8;
      int kk = k0 + row;
      bf16x8 vv = (kk < NQ)
          ? *reinterpret_cast<const bf16x8*>(V + (size_t)(kk * 4 + b) * 256 + cb + dof)
          : bzero8();
#pragma unroll
      for (int j = 0; j < 8; ++j) sVt[dof + j][row] = vv[j];
    }
    __syncthreads();

    f32x4 s[4];
#pragma unroll
    for (int f = 0; f < 4; ++f) {
      bf16x8 bk = *reinterpret_cast<bf16x8*>(&sK[f * 16 + l15][l4 * 8]);
      s[f] = __builtin_amdgcn_mfma_f32_16x16x32_bf16(aq, bk, fzero4(), 0, 0, 0);
    }
#pragma unroll
    for (int f = 0; f < 4; ++f) {
      bool valid = (k0 + f * 16 + l15) < NQ;
#pragma unroll
      for (int i = 0; i < 4; ++i) {
        float sv = s[f][i] * 0.17677669529663687f;
        s[f][i] = valid ? sv : -1e30f;
      }
    }
    float mx[4];
#pragma unroll
    for (int i = 0; i < 4; ++i)
      mx[i] = fmaxf(fmaxf(s[0][i], s[1][i]), fmaxf(s[2][i], s[3][i]));
#pragma unroll
    for (int off = 1; off < 16; off <<= 1)
#pragma unroll
      for (int i = 0; i < 4; ++i) mx[i] = fmaxf(mx[i], __shfl_xor(mx[i], off));

    float alpha[4], rs[4];
#pragma unroll
    for (int i = 0; i < 4; ++i) {
      float mn = fmaxf(mrow[i], mx[i]);
      alpha[i] = __expf(mrow[i] - mn);
      mrow[i] = mn;
      rs[i] = 0.f;
    }
#pragma unroll
    for (int f = 0; f < 4; ++f)
#pragma unroll
      for (int i = 0; i < 4; ++i) {
        float p = __expf(s[f][i] - mrow[i]);
        rs[i] += p;
        sP[wr + l4 * 4 + i][f * 16 + l15] = f2b(p);
      }
#pragma unroll
    for (int off = 1; off < 16; off <<= 1)
#pragma unroll
      for (int i = 0; i < 4; ++i) rs[i] += __shfl_xor(rs[i], off);
#pragma unroll
    for (int i = 0; i < 4; ++i) lrow[i] = lrow[i] * alpha[i] + rs[i];
#pragma unroll
    for (int nf = 0; nf < 2; ++nf)
#pragma unroll
      for (int i = 0; i < 4; ++i) accO[nf][i] *= alpha[i];

#pragma unroll
    for (int ks = 0; ks < 2; ++ks) {
      bf16x8 ap = *reinterpret_cast<bf16x8*>(&sP[wr + l15][ks * 32 + l4 * 8]);
#pragma unroll
      for (int nf = 0; nf < 2; ++nf) {
        bf16x8 bv = *reinterpret_cast<bf16x8*>(&sVt[nf * 16 + l15][ks * 32 + l4 * 8]);
        accO[nf] = __builtin_amdgcn_mfma_f32_16x16x32_bf16(ap, bv, accO[nf], 0, 0, 0);
      }
    }
    __syncthreads();
  }

#pragma unroll
  for (int nf = 0; nf < 2; ++nf)
#pragma unroll
    for (int i = 0; i < 4; ++i) {
      int q = q0 + wr + l4 * 4 + i;
      if (q < NQ)
        O[(size_t)(q * 4 + b) * 256 + cb + nf * 16 + l15] = f2b(accO[nf][i] / lrow[i]);
    }
}

// ------------------------------------------------ residual + LN (+fused bf16 out)
__global__ __launch_bounds__(256) void ln_kernel(const float* __restrict__ A,
                                                 const float* __restrict__ B,
                                                 const float* __restrict__ g,
                                                 const float* __restrict__ bb,
                                                 float* __restrict__ outF,
                                                 short* __restrict__ outB,
                                                 const float* __restrict__ addv) {
  const int row = blockIdx.x;
  const int t = threadIdx.x;
  const size_t base = (size_t)row * D_MODEL;
  float x = A[base + t] + B[base + t];
  float s = x, s2 = x * x;
#pragma unroll
  for (int off = 32; off; off >>= 1) {
    s += __shfl_xor(s, off);
    s2 += __shfl_xor(s2, off);
  }
  __shared__ float wsum[4], wsum2[4];
  const int w = t >> 6;
  if ((t & 63) == 0) { wsum[w] = s; wsum2[w] = s2; }
  __syncthreads();
  s = wsum[0] + wsum[1] + wsum[2] + wsum[3];
  s2 = wsum2[0] + wsum2[1] + wsum2[2] + wsum2[3];
  const float mu = s * (1.f / 256.f);
  const float var = s2 * (1.f / 256.f) - mu * mu;
  const float inv = rsqrtf(var + 1e-5f);
  float y = (x - mu) * inv * g[t] + bb[t];
  outF[base + t] = y;
  if (outB) outB[base + t] = f2b(y + (addv ? addv[base + t] : 0.f));
}

// ------------------------------------------------ MS-deform sampling (bf16 value)
// soaw: (3600,384) fp32: cols 0..255 offsets (h*32 + l*8 + p*2 + c), 256..383 aw.
__global__ __launch_bounds__(256) void msds_kernel(const __hip_bfloat16* __restrict__ value,
                                                   const float* __restrict__ soaw,
                                                   const float* __restrict__ refp,
                                                   __hip_bfloat16* __restrict__ out) {
  const int gid = blockIdx.x * 256 + threadIdx.x;
  const int row = gid >> 8;   // q*4+b
  const int col = gid & 255;
  const int h = col >> 5;
  const int d = col & 31;
  const int b = row & 3;

  const int WL[4] = {128, 64, 32, 16};
  const int ST[4] = {0, 16384, 20480, 21504};

  const float* awp = soaw + (size_t)row * 384 + 256 + h * 16;
  float awv[16];
  float m = -1e30f;
#pragma unroll
  for (int i = 0; i < 16; ++i) { awv[i] = awp[i]; m = fmaxf(m, awv[i]); }
  float s = 0.f;
#pragma unroll
  for (int i = 0; i < 16; ++i) { awv[i] = __expf(awv[i] - m); s += awv[i]; }
  const float invs = 1.f / s;

  const float* offp = soaw + (size_t)row * 384 + h * 32;
  float acc = 0.f;
#pragma unroll
  for (int l = 0; l < 4; ++l) {
    const int wl = WL[l], hl = WL[l], st = ST[l];
    const float rx = refp[((size_t)row * 4 + l) * 2 + 0];
    const float ry = refp[((size_t)row * 4 + l) * 2 + 1];
#pragma unroll
    for (int p = 0; p < 4; ++p) {
      const float ox = offp[l * 8 + p * 2 + 0];
      const float oy = offp[l * 8 + p * 2 + 1];
      const float x = (rx + ox / (float)wl) * (float)wl - 0.5f;
      const float y = (ry + oy / (float)hl) * (float)hl - 0.5f;
      const float x0f = floorf(x), y0f = floorf(y);
      const int x0 = (int)x0f, y0 = (int)y0f;
      const float fx = x - x0f, fy = y - y0f;
      const float a = awv[l * 4 + p] * invs;
      const float w00 = (1.f - fx) * (1.f - fy);
      const float w10 = fx * (1.f - fy);
      const float w01 = (1.f - fx) * fy;
      const float w11 = fx * fy;
      float sum = 0.f;
      if (x0 >= 0 && x0 < wl && y0 >= 0 && y0 < hl)
        sum += w00 * __bfloat162float(value[((size_t)((st + y0 * wl + x0) * 4 + b)) * 256 + h * 32 + d]);
      if (x0 + 1 >= 0 && x0 + 1 < wl && y0 >= 0 && y0 < hl)
        sum += w10 * __bfloat162float(value[((size_t)((st + y0 * wl + x0 + 1) * 4 + b)) * 256 + h * 32 + d]);
      if (x0 >= 0 && x0 < wl && y0 + 1 >= 0 && y0 + 1 < hl)
        sum += w01 * __bfloat162float(value[((size_t)((st + (y0 + 1) * wl + x0) * 4 + b)) * 256 + h * 32 + d]);
      if (x0 + 1 >= 0 && x0 + 1 < wl && y0 + 1 >= 0 && y0 + 1 < hl)
        sum += w11 * __bfloat162float(value[((size_t)((st + (y0 + 1) * wl + x0 + 1) * 4 + b)) * 256 + h * 32 + d]);
      acc += a * sum;
    }
  }
  out[(size_t)row * 256 + col] = __float2bfloat16(acc);
}

// ---------------------------------------------------------------- launch
extern "C" void kernel_launch(void* const* d_in, const int* in_sizes, int n_in,
                              void* d_out, int out_size, void* d_ws, size_t ws_size,
                              hipStream_t stream) {
  const float* tgt      = (const float*)d_in[0];
  const float* qpos     = (const float*)d_in[1];
  const float* memory   = (const float*)d_in[2];
  const float* refp     = (const float*)d_in[3];
  const float* sa_in_w  = (const float*)d_in[4];
  const float* sa_in_b  = (const float*)d_in[5];
  const float* sa_out_w = (const float*)d_in[6];
  const float* sa_out_b = (const float*)d_in[7];
  const float* ln1_g = (const float*)d_in[8];
  const float* ln1_b = (const float*)d_in[9];
  const float* ln2_g = (const float*)d_in[10];
  const float* ln2_b = (const float*)d_in[11];
  const float* ln3_g = (const float*)d_in[12];
  const float* ln3_b = (const float*)d_in[13];
  const float* so_w = (const float*)d_in[14];
  const float* so_b = (const float*)d_in[15];
  const float* aw_w = (const float*)d_in[16];
  const float* aw_b = (const float*)d_in[17];
  const float* vp_w = (const float*)d_in[18];
  const float* vp_b = (const float*)d_in[19];
  const float* op_w = (const float*)d_in[20];
  const float* op_b = (const float*)d_in[21];
  const float* ff1_w = (const float*)d_in[22];
  const float* ff1_b = (const float*)d_in[23];
  const float* ff2_w = (const float*)d_in[24];
  const float* ff2_b = (const float*)d_in[25];

  float* out = (float*)d_out;
  float* ws = (float*)d_ws;

  // ---- workspace layout (floats)
  short* Wb       = (short*)ws;                 // 1,540,096 shorts = 770,048 fl
  float* biasSOAW = ws + 770048;                // 384 fl
  short* tgtb   = (short*)(ws + 770432);        // 460800 fl
  short* qkb    = (short*)(ws + 1231232);       // 460800
  short* QKb    = (short*)(ws + 1692032);       // 921600
  short* Vb     = (short*)(ws + 2613632);       // 460800
  short* Ob     = (short*)(ws + 3074432);       // 460800
  float* SA     = ws + 3535232;                 // 921600
  float* F      = ws + 4456832;                 // 921600
  short* qk2b   = (short*)(ws + 5378432);       // 460800
  float* SOAW   = ws + 5839232;                 // 1382400
  short* value  = (short*)(ws + 7221632);       // 11141120
  short* sampled= (short*)(ws + 18362752);      // 460800
  float* CA     = ws + 18823552;                // 921600
  float* tgt3   = ws + 19745152;                // 921600
  short* tgt3b  = (short*)(ws + 20666752);      // 460800
  short* H      = (short*)(ws + 21127552);      // 3686400
  float* FF     = ws + 24813952;                // 921600

  const short* Wqkv = Wb;
  const short* Wsa  = Wb + 196608;
  const short* Wso  = Wb + 262144;   // so+aw contiguous (384x256)
  const short* Wvp  = Wb + 360448;
  const short* Wop  = Wb + 425984;
  const short* Wff1 = Wb + 491520;
  const short* Wff2 = Wb + 1015808;

  // 0. convert weights + prep activations
  cvt_weights<<<6016, 256, 0, stream>>>(sa_in_w, sa_out_w, so_w, aw_w, vp_w, op_w,
                                        ff1_w, ff2_w, Wb);
  prep_kernel<<<3600, 256, 0, stream>>>(tgt, qpos, tgtb, qkb, so_b, aw_b, biasSOAW);

  // 1. q|k projection (N=512) and v projection
  gemm2<64, 64, 0, 0, 0><<<dim3(57, 8), 256, 0, stream>>>(qkb, Wqkv, sa_in_b, QKb, MROWS, 512, 256);
  gemm2<64, 64, 0, 0, 0><<<dim3(57, 4), 256, 0, stream>>>(tgtb, Wqkv + 512 * 256, sa_in_b + 512, Vb, MROWS, 256, 256);
  // 2. flash attention
  flash_attn<<<dim3(32, 15), 256, 0, stream>>>(QKb, Vb, Ob);
  // 3. sa out projection (fp32 out)
  gemm2<64, 64, 0, 1, 0><<<dim3(57, 4), 256, 0, stream>>>(Ob, Wsa, sa_out_b, SA, MROWS, 256, 256);
  // 4. tgt2 = LN(tgt+sa); qk2b = bf16(tgt2+qpos)
  ln_kernel<<<MROWS, 256, 0, stream>>>(tgt, SA, ln2_g, ln2_b, F, qk2b, qpos);
  // 5. so|aw projection (N=384, fp32 out)
  gemm2<64, 64, 0, 1, 0><<<dim3(57, 6), 256, 0, stream>>>(qk2b, Wso, biasSOAW, SOAW, MROWS, 384, 256);
  // 6. value projection (fp32 in, bf16 out)
  gemm2<64, 256, 1, 0, 0><<<dim3(1360, 1), 256, 0, stream>>>(memory, Wvp, vp_b, value, VROWS, 256, 256);
  // 7. deformable sampling
  msds_kernel<<<MROWS, 256, 0, stream>>>((const __hip_bfloat16*)value, SOAW, refp,
                                         (__hip_bfloat16*)sampled);
  // 8. output projection (fp32 out)
  gemm2<64, 64, 0, 1, 0><<<dim3(57, 4), 256, 0, stream>>>(sampled, Wop, op_b, CA, MROWS, 256, 256);
  // 9. tgt3 = LN(tgt2 + ca); tgt3b bf16
  ln_kernel<<<MROWS, 256, 0, stream>>>(F, CA, ln1_g, ln1_b, tgt3, tgt3b, nullptr);
  // 10. FFN
  gemm2<64, 64, 0, 0, 1><<<dim3(57, 32), 256, 0, stream>>>(tgt3b, Wff1, ff1_b, H, MROWS, 2048, 256);
  gemm2<64, 128, 0, 1, 0><<<dim3(57, 2), 256, 0, stream>>>(H, Wff2, ff2_b, FF, MROWS, 256, 2048);
  // 11. out = LN(tgt3 + ff)
  ln_kernel<<<MROWS, 256, 0, stream>>>(tgt3, FF, ln3_g, ln3_b, out, nullptr, nullptr);
}

// Round 4
// 210.975 us; speedup vs baseline: 5.6921x; 1.1092x over previous
//
#include <hip/hip_runtime.h>
#include <hip/hip_bf16.h>

#define D_MODEL 256
#define N_HEADS 8
#define HD 32
#define NQ 900
#define BS 4
#define MROWS (NQ * BS)          // 3600
#define HW_TOT 21760
#define VROWS (HW_TOT * BS)      // 87040

typedef __attribute__((ext_vector_type(8))) short bf16x8;
typedef __attribute__((ext_vector_type(4))) float f32x4;

__device__ inline short f2b(float f) {
  union { __hip_bfloat16 h; short s; } u;
  u.h = __float2bfloat16(f);
  return u.s;
}
__device__ inline bf16x8 bzero8() {
  bf16x8 v;
#pragma unroll
  for (int j = 0; j < 8; ++j) v[j] = 0;
  return v;
}
__device__ inline f32x4 fzero4() {
  f32x4 v;
#pragma unroll
  for (int j = 0; j < 4; ++j) v[j] = 0.f;
  return v;
}
__device__ inline bf16x8 ldcvt8(const float* __restrict__ p) {
  float4 a = *reinterpret_cast<const float4*>(p);
  float4 b = *reinterpret_cast<const float4*>(p + 4);
  bf16x8 r;
  r[0] = f2b(a.x); r[1] = f2b(a.y); r[2] = f2b(a.z); r[3] = f2b(a.w);
  r[4] = f2b(b.x); r[5] = f2b(b.y); r[6] = f2b(b.z); r[7] = f2b(b.w);
  return r;
}

// ------------------------------------------------ prep: weights + activations
__global__ __launch_bounds__(256) void prep_all(const float* __restrict__ s0,
                                                const float* __restrict__ s1,
                                                const float* __restrict__ s2,
                                                const float* __restrict__ s3,
                                                const float* __restrict__ s4,
                                                const float* __restrict__ s5,
                                                const float* __restrict__ s6,
                                                const float* __restrict__ s7,
                                                short* __restrict__ dst,
                                                const float* __restrict__ tgt,
                                                const float* __restrict__ qpos,
                                                short* __restrict__ tgtb,
                                                short* __restrict__ qkb,
                                                const float* __restrict__ so_b,
                                                const float* __restrict__ aw_b,
                                                float* __restrict__ biasSOAW) {
  int i = blockIdx.x * 256 + threadIdx.x;
  if (i < 1540096) {
    const float* s; int off;
    if (i < 196608)      { s = s0; off = 0; }
    else if (i < 262144) { s = s1; off = 196608; }
    else if (i < 327680) { s = s2; off = 262144; }
    else if (i < 360448) { s = s3; off = 327680; }
    else if (i < 425984) { s = s4; off = 360448; }
    else if (i < 491520) { s = s5; off = 425984; }
    else if (i < 1015808){ s = s6; off = 491520; }
    else                 { s = s7; off = 1015808; }
    dst[i] = f2b(s[i - off]);
  } else {
    int j = i - 1540096;  // < 921600
    float t = tgt[j], p = qpos[j];
    tgtb[j] = f2b(t);
    qkb[j] = f2b(t + p);
    if (j < 384) biasSOAW[j] = (j < 256) ? so_b[j] : aw_b[j - 256];
  }
}

// ------------------------------------------------ generic GEMM core (BM=64)
// out[m0:m0+64, n0:n0+BN] = X @ W^T + bias. LDS stride 40 shorts (80B) kills
// bank conflicts while keeping b128 alignment. Double-buffered, T14-style.
template <int BN, int AF32, int OUTF32, int RELU>
__device__ __forceinline__ void gemm_core(const void* __restrict__ Xv,
                                          const short* __restrict__ W,
                                          const float* __restrict__ bias,
                                          void* __restrict__ outv,
                                          int M, int N, int K, int m0, int n0,
                                          short* __restrict__ smem) {
  constexpr int NF = BN / 16;
  constexpr int NB = BN / 64;
  short* sA = smem;                  // 2 * 64*40
  short* sB = smem + 2 * 64 * 40;    // 2 * BN*40
  const int tid = threadIdx.x;
  const int wave = tid >> 6, lane = tid & 63;
  const int l15 = lane & 15, l4 = lane >> 4;
  const int wr = wave * 16;
  const float* Xf = (const float*)Xv;
  const short* Xh = (const short*)Xv;

  f32x4 acc[NF];
#pragma unroll
  for (int f = 0; f < NF; ++f) acc[f] = fzero4();

  bf16x8 ra, rb[NB];
  const int arow = tid >> 2, akof = (tid & 3) * 8;

  auto loadT = [&](int t) {
    int m = m0 + arow;
    if (m < M) {
      if constexpr (AF32)
        ra = ldcvt8(Xf + (size_t)m * K + t * 32 + akof);
      else
        ra = *reinterpret_cast<const bf16x8*>(Xh + (size_t)m * K + t * 32 + akof);
    } else ra = bzero8();
#pragma unroll
    for (int bb = 0; bb < NB; ++bb) {
      int c = bb * 256 + tid, row = c >> 2, kof = (c & 3) * 8;
      rb[bb] = *reinterpret_cast<const bf16x8*>(W + (size_t)(n0 + row) * K + t * 32 + kof);
    }
  };
  auto storeT = [&](int buf) {
    *reinterpret_cast<bf16x8*>(&sA[buf * 2560 + arow * 40 + akof]) = ra;
#pragma unroll
    for (int bb = 0; bb < NB; ++bb) {
      int c = bb * 256 + tid, row = c >> 2, kof = (c & 3) * 8;
      *reinterpret_cast<bf16x8*>(&sB[buf * BN * 40 + row * 40 + kof]) = rb[bb];
    }
  };
  auto compute = [&](int buf) {
    bf16x8 av = *reinterpret_cast<const bf16x8*>(&sA[buf * 2560 + (wr + l15) * 40 + l4 * 8]);
#pragma unroll
    for (int f = 0; f < NF; ++f) {
      bf16x8 bv = *reinterpret_cast<const bf16x8*>(&sB[buf * BN * 40 + (f * 16 + l15) * 40 + l4 * 8]);
      acc[f] = __builtin_amdgcn_mfma_f32_16x16x32_bf16(av, bv, acc[f], 0, 0, 0);
    }
  };

  const int nt = K / 32;
  loadT(0);
  storeT(0);
  __syncthreads();
  int cur = 0;
  for (int t = 0; t < nt; ++t) {
    if (t + 1 < nt) loadT(t + 1);
    compute(cur);
    if (t + 1 < nt) storeT(cur ^ 1);
    __syncthreads();
    cur ^= 1;
  }

#pragma unroll
  for (int f = 0; f < NF; ++f) {
    int col = n0 + f * 16 + l15;
    float bfv = bias[col];
#pragma unroll
    for (int i = 0; i < 4; ++i) {
      int row = m0 + wr + l4 * 4 + i;
      if (row >= M) continue;
      float v = acc[f][i] + bfv;
      if (RELU) v = fmaxf(v, 0.f);
      if constexpr (OUTF32)
        ((float*)outv)[(size_t)row * N + col] = v;
      else
        ((short*)outv)[(size_t)row * N + col] = f2b(v);
    }
  }
}

template <int BN, int AF32, int OUTF32, int RELU>
__global__ __launch_bounds__(256) void gemm2(const void* __restrict__ Xv,
                                             const short* __restrict__ W,
                                             const float* __restrict__ bias,
                                             void* __restrict__ outv,
                                             int M, int N, int K) {
  __shared__ __align__(16) short smem[2 * 64 * 40 + 2 * BN * 40];
  gemm_core<BN, AF32, OUTF32, RELU>(Xv, W, bias, outv, M, N, K,
                                    blockIdx.x * 64, blockIdx.y * BN, smem);
}

// ------------------------------------------------ q|k and v projections, one dispatch
__global__ __launch_bounds__(256) void qkv_gemm(const short* __restrict__ qkb,
                                                const short* __restrict__ tgtb,
                                                const short* __restrict__ Wqkv,
                                                const float* __restrict__ sa_in_b,
                                                short* __restrict__ QKb,
                                                short* __restrict__ Vb) {
  __shared__ __align__(16) short smem[2 * 64 * 40 + 2 * 64 * 40];
  int bx = blockIdx.x;
  if (bx < 456) {
    gemm_core<64, 0, 0, 0>(qkb, Wqkv, sa_in_b, QKb, MROWS, 512, 256,
                           (bx % 57) * 64, (bx / 57) * 64, smem);
  } else {
    bx -= 456;
    gemm_core<64, 0, 0, 0>(tgtb, Wqkv + 512 * 256, sa_in_b + 512, Vb, MROWS, 256, 256,
                           (bx % 57) * 64, (bx / 57) * 64, smem);
  }
}

// ------------------------------------------------ flash attention body
__device__ __forceinline__ void flash_body(const short* __restrict__ QK,
                                           const short* __restrict__ V,
                                           short* __restrict__ O,
                                           int bid, short* __restrict__ smem) {
  const int bh = bid & 31, b = bh >> 3, h = bh & 7;
  const int q0 = (bid >> 5) * 64;
  const int tid = threadIdx.x, wave = tid >> 6, lane = tid & 63;
  const int l15 = lane & 15, l4 = lane >> 4;
  const int cb = h * 32;

  short* sQ = smem;           // 64*40
  short* sK = smem + 2560;    // 64*40
  short* sVt = smem + 5120;   // 32*72
  short* sP = smem + 7424;    // 64*72

  {
    int row = tid >> 2, kof = (tid & 3) * 8;
    int q = q0 + row;
    bf16x8 v = (q < NQ) ? *reinterpret_cast<const bf16x8*>(QK + (size_t)(q * 4 + b) * 512 + cb + kof)
                        : bzero8();
    *reinterpret_cast<bf16x8*>(&sQ[row * 40 + kof]) = v;
  }
  __syncthreads();
  const int wr = wave * 16;
  const bf16x8 aq = *reinterpret_cast<bf16x8*>(&sQ[(wr + l15) * 40 + l4 * 8]);

  float mrow[4], lrow[4];
#pragma unroll
  for (int i = 0; i < 4; ++i) { mrow[i] = -1e30f; lrow[i] = 0.f; }
  f32x4 accO[2];
  accO[0] = fzero4(); accO[1] = fzero4();

  for (int kt = 0; kt < 15; ++kt) {
    const int k0 = kt * 64;
    {
      int row = tid >> 2, kof = (tid & 3) * 8;
      int kk = k0 + row;
      bf16x8 v = (kk < NQ)
          ? *reinterpret_cast<const bf16x8*>(QK + (size_t)(kk * 4 + b) * 512 + 256 + cb + kof)
          : bzero8();
      *reinterpret_cast<bf16x8*>(&sK[row * 40 + kof]) = v;
    }
    {
      int row = tid >> 2, dof = (tid & 3) * 8;
      int kk = k0 + row;
      bf16x8 vv = (kk < NQ)
          ? *reinterpret_cast<const bf16x8*>(V + (size_t)(kk * 4 + b) * 256 + cb + dof)
          : bzero8();
#pragma unroll
      for (int j = 0; j < 8; ++j) sVt[(dof + j) * 72 + row] = vv[j];
    }
    __syncthreads();

    f32x4 s[4];
#pragma unroll
    for (int f = 0; f < 4; ++f) {
      bf16x8 bk = *reinterpret_cast<bf16x8*>(&sK[(f * 16 + l15) * 40 + l4 * 8]);
      s[f] = __builtin_amdgcn_mfma_f32_16x16x32_bf16(aq, bk, fzero4(), 0, 0, 0);
    }
#pragma unroll
    for (int f = 0; f < 4; ++f) {
      bool valid = (k0 + f * 16 + l15) < NQ;
#pragma unroll
      for (int i = 0; i < 4; ++i) {
        float sv = s[f][i] * 0.17677669529663687f;
        s[f][i] = valid ? sv : -1e30f;
      }
    }
    float mx[4];
#pragma unroll
    for (int i = 0; i < 4; ++i)
      mx[i] = fmaxf(fmaxf(s[0][i], s[1][i]), fmaxf(s[2][i], s[3][i]));
#pragma unroll
    for (int off = 1; off < 16; off <<= 1)
#pragma unroll
      for (int i = 0; i < 4; ++i) mx[i] = fmaxf(mx[i], __shfl_xor(mx[i], off));

    float alpha[4], rs[4];
#pragma unroll
    for (int i = 0; i < 4; ++i) {
      float mn = fmaxf(mrow[i], mx[i]);
      alpha[i] = __expf(mrow[i] - mn);
      mrow[i] = mn;
      rs[i] = 0.f;
    }
#pragma unroll
    for (int f = 0; f < 4; ++f)
#pragma unroll
      for (int i = 0; i < 4; ++i) {
        float p = __expf(s[f][i] - mrow[i]);
        rs[i] += p;
        sP[(wr + l4 * 4 + i) * 72 + f * 16 + l15] = f2b(p);
      }
#pragma unroll
    for (int off = 1; off < 16; off <<= 1)
#pragma unroll
      for (int i = 0; i < 4; ++i) rs[i] += __shfl_xor(rs[i], off);
#pragma unroll
    for (int i = 0; i < 4; ++i) lrow[i] = lrow[i] * alpha[i] + rs[i];
#pragma unroll
    for (int nf = 0; nf < 2; ++nf)
#pragma unroll
      for (int i = 0; i < 4; ++i) accO[nf][i] *= alpha[i];

#pragma unroll
    for (int ks = 0; ks < 2; ++ks) {
      bf16x8 ap = *reinterpret_cast<bf16x8*>(&sP[(wr + l15) * 72 + ks * 32 + l4 * 8]);
#pragma unroll
      for (int nf = 0; nf < 2; ++nf) {
        bf16x8 bv = *reinterpret_cast<bf16x8*>(&sVt[(nf * 16 + l15) * 72 + ks * 32 + l4 * 8]);
        accO[nf] = __builtin_amdgcn_mfma_f32_16x16x32_bf16(ap, bv, accO[nf], 0, 0, 0);
      }
    }
    __syncthreads();
  }

#pragma unroll
  for (int nf = 0; nf < 2; ++nf)
#pragma unroll
    for (int i = 0; i < 4; ++i) {
      int q = q0 + wr + l4 * 4 + i;
      if (q < NQ)
        O[(size_t)(q * 4 + b) * 256 + cb + nf * 16 + l15] = f2b(accO[nf][i] / lrow[i]);
    }
}

// ------------------------------------------------ hetero: flash || value proj
__global__ __launch_bounds__(256) void flash_value(const short* __restrict__ QKb,
                                                   const short* __restrict__ Vb,
                                                   short* __restrict__ Ob,
                                                   const float* __restrict__ memory,
                                                   const short* __restrict__ Wvp,
                                                   const float* __restrict__ vp_b,
                                                   short* __restrict__ value) {
  __shared__ __align__(16) short smem[2 * 64 * 40 + 2 * 256 * 40];  // 51200 B
  int bx = blockIdx.x;
  if (bx < 480) {
    flash_body(QKb, Vb, Ob, bx, smem);
  } else {
    bx -= 480;
    gemm_core<256, 1, 0, 0>(memory, Wvp, vp_b, value, VROWS, 256, 256,
                            bx * 64, 0, smem);
  }
}

// ------------------------------------------------ residual + LN (+fused bf16 out)
__global__ __launch_bounds__(256) void ln_kernel(const float* __restrict__ A,
                                                 const float* __restrict__ B,
                                                 const float* __restrict__ g,
                                                 const float* __restrict__ bb,
                                                 float* __restrict__ outF,
                                                 short* __restrict__ outB,
                                                 const float* __restrict__ addv) {
  const int row = blockIdx.x;
  const int t = threadIdx.x;
  const size_t base = (size_t)row * D_MODEL;
  float x = A[base + t] + B[base + t];
  float s = x, s2 = x * x;
#pragma unroll
  for (int off = 32; off; off >>= 1) {
    s += __shfl_xor(s, off);
    s2 += __shfl_xor(s2, off);
  }
  __shared__ float wsum[4], wsum2[4];
  const int w = t >> 6;
  if ((t & 63) == 0) { wsum[w] = s; wsum2[w] = s2; }
  __syncthreads();
  s = wsum[0] + wsum[1] + wsum[2] + wsum[3];
  s2 = wsum2[0] + wsum2[1] + wsum2[2] + wsum2[3];
  const float mu = s * (1.f / 256.f);
  const float var = s2 * (1.f / 256.f) - mu * mu;
  const float inv = rsqrtf(var + 1e-5f);
  float y = (x - mu) * inv * g[t] + bb[t];
  outF[base + t] = y;
  if (outB) outB[base + t] = f2b(y + (addv ? addv[base + t] : 0.f));
}

// ------------------------------------------------ MS-deform sampling (2-wide)
// Block = 2 rows x 128 cols; each thread handles 2 consecutive d.
__global__ __launch_bounds__(256) void msds_kernel(const unsigned short* __restrict__ value,
                                                   const float* __restrict__ soaw,
                                                   const float* __restrict__ refp,
                                                   unsigned int* __restrict__ out) {
  const int tid = threadIdx.x;
  const int row = blockIdx.x * 2 + (tid >> 7);  // q*4+b
  const int col2 = tid & 127;
  const int h = col2 >> 4;
  const int dp = (col2 & 15) * 2;
  const int b = row & 3;

  const int WL[4] = {128, 64, 32, 16};
  const int ST[4] = {0, 16384, 20480, 21504};

  const float* awp = soaw + (size_t)row * 384 + 256 + h * 16;
  float awv[16];
  float m = -1e30f;
#pragma unroll
  for (int i = 0; i < 16; ++i) { awv[i] = awp[i]; m = fmaxf(m, awv[i]); }
  float s = 0.f;
#pragma unroll
  for (int i = 0; i < 16; ++i) { awv[i] = __expf(awv[i] - m); s += awv[i]; }
  const float invs = 1.f / s;

  const float* offp = soaw + (size_t)row * 384 + h * 32;
  float acc0 = 0.f, acc1 = 0.f;
#pragma unroll
  for (int l = 0; l < 4; ++l) {
    const int wl = WL[l], hl = WL[l], st = ST[l];
    const float rx = refp[((size_t)row * 4 + l) * 2 + 0];
    const float ry = refp[((size_t)row * 4 + l) * 2 + 1];
#pragma unroll
    for (int p = 0; p < 4; ++p) {
      const float ox = offp[l * 8 + p * 2 + 0];
      const float oy = offp[l * 8 + p * 2 + 1];
      const float x = (rx + ox / (float)wl) * (float)wl - 0.5f;
      const float y = (ry + oy / (float)hl) * (float)hl - 0.5f;
      const float x0f = floorf(x), y0f = floorf(y);
      const int x0 = (int)x0f, y0 = (int)y0f;
      const float fx = x - x0f, fy = y - y0f;
      const float a = awv[l * 4 + p] * invs;
      const float w00 = (1.f - fx) * (1.f - fy);
      const float w10 = fx * (1.f - fy);
      const float w01 = (1.f - fx) * fy;
      const float w11 = fx * fy;
      float s0 = 0.f, s1 = 0.f;
      auto gat = [&](int ix, int iy, float wgt) {
        if (ix >= 0 && ix < wl && iy >= 0 && iy < hl) {
          const unsigned short* p2 =
              value + ((size_t)((st + iy * wl + ix) * 4 + b)) * 256 + h * 32 + dp;
          unsigned int u = *reinterpret_cast<const unsigned int*>(p2);
          union { unsigned int ui; __hip_bfloat162 h2; } cv; cv.ui = u;
          s0 += wgt * __bfloat162float(cv.h2.x);
          s1 += wgt * __bfloat162float(cv.h2.y);
        }
      };
      gat(x0, y0, w00);
      gat(x0 + 1, y0, w10);
      gat(x0, y0 + 1, w01);
      gat(x0 + 1, y0 + 1, w11);
      acc0 += a * s0;
      acc1 += a * s1;
    }
  }
  union { unsigned int ui; struct { unsigned short a, b; } ss; } o;
  o.ss.a = (unsigned short)f2b(acc0);
  o.ss.b = (unsigned short)f2b(acc1);
  out[((size_t)row * 256 + h * 32 + dp) >> 1] = o.ui;
}

// ---------------------------------------------------------------- launch
extern "C" void kernel_launch(void* const* d_in, const int* in_sizes, int n_in,
                              void* d_out, int out_size, void* d_ws, size_t ws_size,
                              hipStream_t stream) {
  const float* tgt      = (const float*)d_in[0];
  const float* qpos     = (const float*)d_in[1];
  const float* memory   = (const float*)d_in[2];
  const float* refp     = (const float*)d_in[3];
  const float* sa_in_w  = (const float*)d_in[4];
  const float* sa_in_b  = (const float*)d_in[5];
  const float* sa_out_w = (const float*)d_in[6];
  const float* sa_out_b = (const float*)d_in[7];
  const float* ln1_g = (const float*)d_in[8];
  const float* ln1_b = (const float*)d_in[9];
  const float* ln2_g = (const float*)d_in[10];
  const float* ln2_b = (const float*)d_in[11];
  const float* ln3_g = (const float*)d_in[12];
  const float* ln3_b = (const float*)d_in[13];
  const float* so_w = (const float*)d_in[14];
  const float* so_b = (const float*)d_in[15];
  const float* aw_w = (const float*)d_in[16];
  const float* aw_b = (const float*)d_in[17];
  const float* vp_w = (const float*)d_in[18];
  const float* vp_b = (const float*)d_in[19];
  const float* op_w = (const float*)d_in[20];
  const float* op_b = (const float*)d_in[21];
  const float* ff1_w = (const float*)d_in[22];
  const float* ff1_b = (const float*)d_in[23];
  const float* ff2_w = (const float*)d_in[24];
  const float* ff2_b = (const float*)d_in[25];

  float* out = (float*)d_out;
  float* ws = (float*)d_ws;

  short* Wb       = (short*)ws;                 // 1,540,096 shorts
  float* biasSOAW = ws + 770048;
  short* tgtb   = (short*)(ws + 770432);
  short* qkb    = (short*)(ws + 1231232);
  short* QKb    = (short*)(ws + 1692032);
  short* Vb     = (short*)(ws + 2613632);
  short* Ob     = (short*)(ws + 3074432);
  float* SA     = ws + 3535232;
  float* F      = ws + 4456832;
  short* qk2b   = (short*)(ws + 5378432);
  float* SOAW   = ws + 5839232;
  short* value  = (short*)(ws + 7221632);
  short* sampled= (short*)(ws + 18362752);
  float* CA     = ws + 18823552;
  float* tgt3   = ws + 19745152;
  short* tgt3b  = (short*)(ws + 20666752);
  short* H      = (short*)(ws + 21127552);
  float* FF     = ws + 24813952;

  const short* Wqkv = Wb;
  const short* Wsa  = Wb + 196608;
  const short* Wso  = Wb + 262144;
  const short* Wvp  = Wb + 360448;
  const short* Wop  = Wb + 425984;
  const short* Wff1 = Wb + 491520;
  const short* Wff2 = Wb + 1015808;

  // 0. weights + activations prep (one dispatch)
  prep_all<<<9616, 256, 0, stream>>>(sa_in_w, sa_out_w, so_w, aw_w, vp_w, op_w,
                                     ff1_w, ff2_w, Wb, tgt, qpos, tgtb, qkb,
                                     so_b, aw_b, biasSOAW);
  // 1. q|k + v projections (hetero, 684 blocks)
  qkv_gemm<<<684, 256, 0, stream>>>(qkb, tgtb, Wqkv, sa_in_b, QKb, Vb);
  // 2. flash attention || value projection (hetero, 480+1360 blocks)
  flash_value<<<1840, 256, 0, stream>>>(QKb, Vb, Ob, memory, Wvp, vp_b, value);
  // 3. sa out projection (fp32 out)
  gemm2<64, 0, 1, 0><<<dim3(57, 4), 256, 0, stream>>>(Ob, Wsa, sa_out_b, SA, MROWS, 256, 256);
  // 4. tgt2 = LN(tgt+sa) [ln2]; qk2b = bf16(tgt2+qpos)
  ln_kernel<<<MROWS, 256, 0, stream>>>(tgt, SA, ln2_g, ln2_b, F, qk2b, qpos);
  // 5. so|aw projection (N=384, fp32 out)
  gemm2<64, 0, 1, 0><<<dim3(57, 6), 256, 0, stream>>>(qk2b, Wso, biasSOAW, SOAW, MROWS, 384, 256);
  // 6. deformable sampling
  msds_kernel<<<1800, 256, 0, stream>>>((const unsigned short*)value, SOAW, refp,
                                        (unsigned int*)sampled);
  // 7. output projection (fp32 out)
  gemm2<64, 0, 1, 0><<<dim3(57, 4), 256, 0, stream>>>(sampled, Wop, op_b, CA, MROWS, 256, 256);
  // 8. tgt3 = LN(tgt2 + ca) [ln1]
  ln_kernel<<<MROWS, 256, 0, stream>>>(F, CA, ln1_g, ln1_b, tgt3, tgt3b, nullptr);
  // 9. FFN
  gemm2<64, 0, 0, 1><<<dim3(57, 32), 256, 0, stream>>>(tgt3b, Wff1, ff1_b, H, MROWS, 2048, 256);
  gemm2<64, 0, 1, 0><<<dim3(57, 4), 256, 0, stream>>>(H, Wff2, ff2_b, FF, MROWS, 256, 2048);
  // 10. out = LN(tgt3 + ff) [ln3]
  ln_kernel<<<MROWS, 256, 0, stream>>>(tgt3, FF, ln3_g, ln3_b, out, nullptr, nullptr);
}